// Round 7
// baseline (3044.655 us; speedup 1.0000x reference)
//
#include <hip/hip_runtime.h>

#define BATCH 32
#define N 1024
#define EPS 0.001f
#define ITERS 10
#define TR 32              // rows per block tile (LDS-resident fp8)
#define NCH (N / TR)       // 32 row-chunk blocks per batch; grid = 32 x 32

typedef float v2f __attribute__((vector_size(8)));

// ws layout: part[BATCH*NCH*N] f32 (4 MB) | c[BATCH*N] f32 (128 KB)
//          | bar[2*ITERS*BATCH] int (2.5 KB, memset to 0 each launch)

__device__ __forceinline__ float dot16_fp8(const int4 raw, const float* creg) {
    float s = 0.0f;
    v2f f;
    f = __builtin_amdgcn_cvt_pk_f32_fp8(raw.x, false); s += creg[0]*f[0]  + creg[1]*f[1];
    f = __builtin_amdgcn_cvt_pk_f32_fp8(raw.x, true);  s += creg[2]*f[0]  + creg[3]*f[1];
    f = __builtin_amdgcn_cvt_pk_f32_fp8(raw.y, false); s += creg[4]*f[0]  + creg[5]*f[1];
    f = __builtin_amdgcn_cvt_pk_f32_fp8(raw.y, true);  s += creg[6]*f[0]  + creg[7]*f[1];
    f = __builtin_amdgcn_cvt_pk_f32_fp8(raw.z, false); s += creg[8]*f[0]  + creg[9]*f[1];
    f = __builtin_amdgcn_cvt_pk_f32_fp8(raw.z, true);  s += creg[10]*f[0] + creg[11]*f[1];
    f = __builtin_amdgcn_cvt_pk_f32_fp8(raw.w, false); s += creg[12]*f[0] + creg[13]*f[1];
    f = __builtin_amdgcn_cvt_pk_f32_fp8(raw.w, true);  s += creg[14]*f[0] + creg[15]*f[1];
    return s;
}

__device__ __forceinline__ void load_creg(const float* cb, float* creg) {
    float4 c0 = *(const float4*)(cb);
    float4 c1 = *(const float4*)(cb + 4);
    float4 c2 = *(const float4*)(cb + 8);
    float4 c3 = *(const float4*)(cb + 12);
    creg[0]=c0.x;  creg[1]=c0.y;  creg[2]=c0.z;  creg[3]=c0.w;
    creg[4]=c1.x;  creg[5]=c1.y;  creg[6]=c1.z;  creg[7]=c1.w;
    creg[8]=c2.x;  creg[9]=c2.y;  creg[10]=c2.z; creg[11]=c2.w;
    creg[12]=c3.x; creg[13]=c3.y; creg[14]=c3.z; creg[15]=c3.w;
}

// Release/acquire barrier among the NCH blocks of one batch.
// Producer block: __syncthreads (drains this block's vmem), thread0 does a
// device-scope release fence + arrival atomic, then spins (bounded) until all
// NCH blocks arrived; trailing fence gives every thread acquire semantics.
__device__ __forceinline__ void batch_barrier(int* ctr) {
    __syncthreads();
    if (threadIdx.x == 0) {
        __threadfence();                    // release: publish this block's stores
        atomicAdd(ctr, 1);                  // device-scope (G12)
        int spins = 0;
        while (__hip_atomic_load(ctr, __ATOMIC_ACQUIRE, __HIP_MEMORY_SCOPE_AGENT) < NCH
               && spins < (1 << 24)) {      // bounded: deadlock -> clean fail, not hang
            __builtin_amdgcn_s_sleep(1);
            ++spins;
        }
    }
    __syncthreads();
    __threadfence();                        // acquire for all threads' subsequent reads
}

__global__ __launch_bounds__(256, 4)
void sink_persistent(const float* __restrict__ x,
                     float* __restrict__ part,
                     float* __restrict__ c,
                     int* __restrict__ bar,
                     float* __restrict__ out) {
    __shared__ __align__(16) unsigned char tile[TR * N];   // 32 KB fp8 tile
    __shared__ float r_sh[TR];
    __shared__ float red[8][TR];                           // c-reduce scratch
    const int chunk = blockIdx.x, b = blockIdx.y;
    const int tid = threadIdx.x;
    const int wave = tid >> 6, lane = tid & 63;
    const int j0 = lane * 16;
    const size_t row0 = (size_t)b * N + (size_t)chunk * TR;

    // ---- stage: fp32 rows -> fp8 LDS; exact-fp32 rowsum with c0 = 1 ----
    for (int il = 0; il < TR / 4; ++il) {
        const int rl = wave * (TR / 4) + il;
        const float* xr = x + (row0 + rl) * N + j0;
        float4 v0 = *(const float4*)(xr);
        float4 v1 = *(const float4*)(xr + 4);
        float4 v2 = *(const float4*)(xr + 8);
        float4 v3 = *(const float4*)(xr + 12);
        float a0=v0.x+EPS, a1=v0.y+EPS, a2=v0.z+EPS, a3=v0.w+EPS;
        float a4=v1.x+EPS, a5=v1.y+EPS, a6=v1.z+EPS, a7=v1.w+EPS;
        float a8=v2.x+EPS, a9=v2.y+EPS, a10=v2.z+EPS, a11=v2.w+EPS;
        float a12=v3.x+EPS, a13=v3.y+EPS, a14=v3.z+EPS, a15=v3.w+EPS;
        int4 q;
        q.x = __builtin_amdgcn_cvt_pk_fp8_f32(a0, a1, 0, false);
        q.x = __builtin_amdgcn_cvt_pk_fp8_f32(a2, a3, q.x, true);
        q.y = __builtin_amdgcn_cvt_pk_fp8_f32(a4, a5, 0, false);
        q.y = __builtin_amdgcn_cvt_pk_fp8_f32(a6, a7, q.y, true);
        q.z = __builtin_amdgcn_cvt_pk_fp8_f32(a8, a9, 0, false);
        q.z = __builtin_amdgcn_cvt_pk_fp8_f32(a10, a11, q.z, true);
        q.w = __builtin_amdgcn_cvt_pk_fp8_f32(a12, a13, 0, false);
        q.w = __builtin_amdgcn_cvt_pk_fp8_f32(a14, a15, q.w, true);
        *(int4*)(&tile[rl * N + j0]) = q;
        float sum = ((a0+a1)+(a2+a3)) + ((a4+a5)+(a6+a7))
                  + ((a8+a9)+(a10+a11)) + ((a12+a13)+(a14+a15));
#pragma unroll
        for (int off = 32; off; off >>= 1) sum += __shfl_xor(sum, off);
        if (!lane) r_sh[rl] = 1.0f / sum;
    }

    // ---- iterations ----
    for (int t = 0; t < ITERS; ++t) {
        __syncthreads();                    // r_sh / tile ready
        // col partials: thread owns 4 consecutive columns
        const int jc = tid * 4;
        float s0 = 0, s1 = 0, s2 = 0, s3 = 0;
#pragma unroll 8
        for (int i = 0; i < TR; ++i) {
            float rv = r_sh[i];
            int w = *(const int*)(&tile[i * N + jc]);
            v2f f01 = __builtin_amdgcn_cvt_pk_f32_fp8(w, false);
            v2f f23 = __builtin_amdgcn_cvt_pk_f32_fp8(w, true);
            s0 += rv * f01[0];  s1 += rv * f01[1];
            s2 += rv * f23[0];  s3 += rv * f23[1];
        }
        *(float4*)(part + ((size_t)(b * NCH + chunk)) * N + jc) =
            make_float4(s0, s1, s2, s3);

        batch_barrier(bar + (2 * t) * BATCH + b);       // part[b,:,:] ready

        // c-reduce for this block's 32-column slice, all 256 threads:
        // thread (g, jj): partial over 4 chunks; then 8-way LDS combine.
        {
            const int g = tid >> 5, jj = tid & 31;
            const int j = chunk * TR + jj;
            const float* pp = part + (size_t)b * NCH * N + j;
            float s = pp[(size_t)(g * 4 + 0) * N] + pp[(size_t)(g * 4 + 1) * N]
                    + pp[(size_t)(g * 4 + 2) * N] + pp[(size_t)(g * 4 + 3) * N];
            red[g][jj] = s;
            __syncthreads();
            if (tid < TR) {
                float tt = 0.0f;
#pragma unroll
                for (int gg = 0; gg < 8; ++gg) tt += red[gg][tid];
                c[b * N + chunk * TR + tid] = 1.0f / tt;
            }
        }

        batch_barrier(bar + (2 * t + 1) * BATCH + b);   // c[b,:] ready

        if (t < ITERS - 1) {
            float creg[16];
            load_creg(c + b * N + j0, creg);
            for (int il = 0; il < TR / 4; ++il) {
                const int rl = wave * (TR / 4) + il;
                int4 raw = *(const int4*)(&tile[rl * N + j0]);
                float sum = dot16_fp8(raw, creg);
#pragma unroll
                for (int off = 32; off; off >>= 1) sum += __shfl_xor(sum, off);
                if (!lane) r_sh[rl] = 1.0f / sum;
            }
        }
    }

    // ---- final: out = r * (x + eps) * c, full fp32 precision ----
    float creg[16];
    load_creg(c + b * N + j0, creg);
    for (int il = 0; il < TR / 4; ++il) {
        const int rl = wave * (TR / 4) + il;
        const float rv = r_sh[rl];
        const float* xr = x + (row0 + rl) * N + j0;
        float* orow = out + (row0 + rl) * N + j0;
        float4 v0 = *(const float4*)(xr);
        float4 v1 = *(const float4*)(xr + 4);
        float4 v2 = *(const float4*)(xr + 8);
        float4 v3 = *(const float4*)(xr + 12);
        float4 o;
        o = make_float4(rv*(v0.x+EPS)*creg[0],  rv*(v0.y+EPS)*creg[1],
                        rv*(v0.z+EPS)*creg[2],  rv*(v0.w+EPS)*creg[3]);
        *(float4*)(orow) = o;
        o = make_float4(rv*(v1.x+EPS)*creg[4],  rv*(v1.y+EPS)*creg[5],
                        rv*(v1.z+EPS)*creg[6],  rv*(v1.w+EPS)*creg[7]);
        *(float4*)(orow + 4) = o;
        o = make_float4(rv*(v2.x+EPS)*creg[8],  rv*(v2.y+EPS)*creg[9],
                        rv*(v2.z+EPS)*creg[10], rv*(v2.w+EPS)*creg[11]);
        *(float4*)(orow + 8) = o;
        o = make_float4(rv*(v3.x+EPS)*creg[12], rv*(v3.y+EPS)*creg[13],
                        rv*(v3.z+EPS)*creg[14], rv*(v3.w+EPS)*creg[15]);
        *(float4*)(orow + 12) = o;
    }
}

extern "C" void kernel_launch(void* const* d_in, const int* in_sizes, int n_in,
                              void* d_out, int out_size, void* d_ws, size_t ws_size,
                              hipStream_t stream) {
    const float* x = (const float*)d_in[0];
    float* out  = (float*)d_out;
    float* part = (float*)d_ws;
    float* c    = part + BATCH * NCH * N;
    int*   bar  = (int*)(c + BATCH * N);

    // zero barrier counters every call (graph-capturable stream op)
    hipMemsetAsync(bar, 0, 2 * ITERS * BATCH * sizeof(int), stream);

    sink_persistent<<<dim3(NCH, BATCH), 256, 0, stream>>>(x, part, c, bar, out);
}

// Round 8
// 986.809 us; speedup vs baseline: 3.0854x; 3.0854x over previous
//
#include <hip/hip_runtime.h>

#define BATCH 32
#define N 1024
#define EPS 0.001f
#define ITERS 10
#define TR 32              // rows per block tile (LDS-resident fp8)
#define NCH (N / TR)       // 32 row-chunk blocks per batch; grid = 32 x 32

typedef float v2f __attribute__((vector_size(8)));

// ws layout: part[BATCH*NCH*N] f32 (4 MB) | c[BATCH*N] f32 (128 KB)
//          | bar[2*ITERS*BATCH] int (2.5 KB, memset to 0 each launch)
//
// part/c are cross-block message buffers: ALL accesses to them are relaxed
// agent-scope atomics (sc0 sc1 -> coherence point, bypass L1/L2 caching).
// No __threadfence anywhere: __syncthreads drains vmcnt per wave, which
// retires the coherent stores at the coherence point (release); readers use
// coherent loads (acquire-by-construction). This avoids the buffer_wbl2 /
// buffer_inv storms that made the R7 fence-based barrier 14x slow.

__device__ __forceinline__ float coh_ld(const float* p) {
    return __hip_atomic_load(p, __ATOMIC_RELAXED, __HIP_MEMORY_SCOPE_AGENT);
}
__device__ __forceinline__ void coh_st(float* p, float v) {
    __hip_atomic_store(p, v, __ATOMIC_RELAXED, __HIP_MEMORY_SCOPE_AGENT);
}

__device__ __forceinline__ float dot16_fp8(const int4 raw, const float* creg) {
    float s = 0.0f;
    v2f f;
    f = __builtin_amdgcn_cvt_pk_f32_fp8(raw.x, false); s += creg[0]*f[0]  + creg[1]*f[1];
    f = __builtin_amdgcn_cvt_pk_f32_fp8(raw.x, true);  s += creg[2]*f[0]  + creg[3]*f[1];
    f = __builtin_amdgcn_cvt_pk_f32_fp8(raw.y, false); s += creg[4]*f[0]  + creg[5]*f[1];
    f = __builtin_amdgcn_cvt_pk_f32_fp8(raw.y, true);  s += creg[6]*f[0]  + creg[7]*f[1];
    f = __builtin_amdgcn_cvt_pk_f32_fp8(raw.z, false); s += creg[8]*f[0]  + creg[9]*f[1];
    f = __builtin_amdgcn_cvt_pk_f32_fp8(raw.z, true);  s += creg[10]*f[0] + creg[11]*f[1];
    f = __builtin_amdgcn_cvt_pk_f32_fp8(raw.w, false); s += creg[12]*f[0] + creg[13]*f[1];
    f = __builtin_amdgcn_cvt_pk_f32_fp8(raw.w, true);  s += creg[14]*f[0] + creg[15]*f[1];
    return s;
}

// Barrier among the NCH blocks of one batch. Entry __syncthreads drains every
// wave's outstanding vmem (compiler emits s_waitcnt vmcnt(0) before s_barrier),
// so all coherent stores are globally visible before the relaxed arrival add.
__device__ __forceinline__ void batch_barrier(int* ctr) {
    asm volatile("s_waitcnt vmcnt(0)" ::: "memory");
    __syncthreads();
    if (threadIdx.x == 0) {
        __hip_atomic_fetch_add(ctr, 1, __ATOMIC_RELAXED, __HIP_MEMORY_SCOPE_AGENT);
        int spins = 0;
        while (__hip_atomic_load(ctr, __ATOMIC_RELAXED, __HIP_MEMORY_SCOPE_AGENT) < NCH
               && spins < (1 << 20)) {      // bounded: deadlock -> clean fail
            __builtin_amdgcn_s_sleep(2);
            ++spins;
        }
    }
    __syncthreads();
}

__global__ __launch_bounds__(256, 4)
void sink_persistent(const float* __restrict__ x,
                     float* __restrict__ part,
                     float* __restrict__ c,
                     int* __restrict__ bar,
                     float* __restrict__ out) {
    __shared__ __align__(16) unsigned char tile[TR * N];   // 32 KB fp8 tile
    __shared__ float r_sh[TR];
    __shared__ float red[8][TR];                           // c-reduce scratch
    const int chunk = blockIdx.x, b = blockIdx.y;
    const int tid = threadIdx.x;
    const int wave = tid >> 6, lane = tid & 63;
    const int j0 = lane * 16;
    const size_t row0 = (size_t)b * N + (size_t)chunk * TR;

    // ---- stage: fp32 rows -> fp8 LDS; exact-fp32 rowsum with c0 = 1 ----
    for (int il = 0; il < TR / 4; ++il) {
        const int rl = wave * (TR / 4) + il;
        const float* xr = x + (row0 + rl) * N + j0;
        float4 v0 = *(const float4*)(xr);
        float4 v1 = *(const float4*)(xr + 4);
        float4 v2 = *(const float4*)(xr + 8);
        float4 v3 = *(const float4*)(xr + 12);
        float a0=v0.x+EPS, a1=v0.y+EPS, a2=v0.z+EPS, a3=v0.w+EPS;
        float a4=v1.x+EPS, a5=v1.y+EPS, a6=v1.z+EPS, a7=v1.w+EPS;
        float a8=v2.x+EPS, a9=v2.y+EPS, a10=v2.z+EPS, a11=v2.w+EPS;
        float a12=v3.x+EPS, a13=v3.y+EPS, a14=v3.z+EPS, a15=v3.w+EPS;
        int4 q;
        q.x = __builtin_amdgcn_cvt_pk_fp8_f32(a0, a1, 0, false);
        q.x = __builtin_amdgcn_cvt_pk_fp8_f32(a2, a3, q.x, true);
        q.y = __builtin_amdgcn_cvt_pk_fp8_f32(a4, a5, 0, false);
        q.y = __builtin_amdgcn_cvt_pk_fp8_f32(a6, a7, q.y, true);
        q.z = __builtin_amdgcn_cvt_pk_fp8_f32(a8, a9, 0, false);
        q.z = __builtin_amdgcn_cvt_pk_fp8_f32(a10, a11, q.z, true);
        q.w = __builtin_amdgcn_cvt_pk_fp8_f32(a12, a13, 0, false);
        q.w = __builtin_amdgcn_cvt_pk_fp8_f32(a14, a15, q.w, true);
        *(int4*)(&tile[rl * N + j0]) = q;
        float sum = ((a0+a1)+(a2+a3)) + ((a4+a5)+(a6+a7))
                  + ((a8+a9)+(a10+a11)) + ((a12+a13)+(a14+a15));
#pragma unroll
        for (int off = 32; off; off >>= 1) sum += __shfl_xor(sum, off);
        if (!lane) r_sh[rl] = 1.0f / sum;
    }

    // ---- iterations ----
    for (int t = 0; t < ITERS; ++t) {
        __syncthreads();                    // r_sh / tile ready
        // col partials: thread owns 4 consecutive columns
        const int jc = tid * 4;
        float s0 = 0, s1 = 0, s2 = 0, s3 = 0;
#pragma unroll 8
        for (int i = 0; i < TR; ++i) {
            float rv = r_sh[i];
            int w = *(const int*)(&tile[i * N + jc]);
            v2f f01 = __builtin_amdgcn_cvt_pk_f32_fp8(w, false);
            v2f f23 = __builtin_amdgcn_cvt_pk_f32_fp8(w, true);
            s0 += rv * f01[0];  s1 += rv * f01[1];
            s2 += rv * f23[0];  s3 += rv * f23[1];
        }
        {
            float* pb = part + ((size_t)(b * NCH + chunk)) * N + jc;
            coh_st(pb + 0, s0); coh_st(pb + 1, s1);
            coh_st(pb + 2, s2); coh_st(pb + 3, s3);
        }

        batch_barrier(bar + (2 * t) * BATCH + b);       // part[b,:,:] visible

        // c-reduce for this block's 32-column slice, all 256 threads:
        // thread (g, jj): partial over 4 chunks; 8-way LDS combine.
        {
            const int g = tid >> 5, jj = tid & 31;
            const int j = chunk * TR + jj;
            const float* pp = part + (size_t)b * NCH * N + j;
            float s = coh_ld(pp + (size_t)(g * 4 + 0) * N)
                    + coh_ld(pp + (size_t)(g * 4 + 1) * N)
                    + coh_ld(pp + (size_t)(g * 4 + 2) * N)
                    + coh_ld(pp + (size_t)(g * 4 + 3) * N);
            red[g][jj] = s;
            __syncthreads();
            if (tid < TR) {
                float tt = 0.0f;
#pragma unroll
                for (int gg = 0; gg < 8; ++gg) tt += red[gg][tid];
                coh_st(c + b * N + chunk * TR + tid, 1.0f / tt);
            }
        }

        batch_barrier(bar + (2 * t + 1) * BATCH + b);   // c[b,:] visible

        if (t < ITERS - 1) {
            float creg[16];
            const float* cb = c + b * N + j0;
#pragma unroll
            for (int k = 0; k < 16; ++k) creg[k] = coh_ld(cb + k);
            for (int il = 0; il < TR / 4; ++il) {
                const int rl = wave * (TR / 4) + il;
                int4 raw = *(const int4*)(&tile[rl * N + j0]);
                float sum = dot16_fp8(raw, creg);
#pragma unroll
                for (int off = 32; off; off >>= 1) sum += __shfl_xor(sum, off);
                if (!lane) r_sh[rl] = 1.0f / sum;
            }
        }
    }

    // ---- final: out = r * (x + eps) * c, full fp32 precision ----
    float creg[16];
    {
        const float* cb = c + b * N + j0;
#pragma unroll
        for (int k = 0; k < 16; ++k) creg[k] = coh_ld(cb + k);
    }
    for (int il = 0; il < TR / 4; ++il) {
        const int rl = wave * (TR / 4) + il;
        const float rv = r_sh[rl];
        const float* xr = x + (row0 + rl) * N + j0;
        float* orow = out + (row0 + rl) * N + j0;
        float4 v0 = *(const float4*)(xr);
        float4 v1 = *(const float4*)(xr + 4);
        float4 v2 = *(const float4*)(xr + 8);
        float4 v3 = *(const float4*)(xr + 12);
        float4 o;
        o = make_float4(rv*(v0.x+EPS)*creg[0],  rv*(v0.y+EPS)*creg[1],
                        rv*(v0.z+EPS)*creg[2],  rv*(v0.w+EPS)*creg[3]);
        *(float4*)(orow) = o;
        o = make_float4(rv*(v1.x+EPS)*creg[4],  rv*(v1.y+EPS)*creg[5],
                        rv*(v1.z+EPS)*creg[6],  rv*(v1.w+EPS)*creg[7]);
        *(float4*)(orow + 4) = o;
        o = make_float4(rv*(v2.x+EPS)*creg[8],  rv*(v2.y+EPS)*creg[9],
                        rv*(v2.z+EPS)*creg[10], rv*(v2.w+EPS)*creg[11]);
        *(float4*)(orow + 8) = o;
        o = make_float4(rv*(v3.x+EPS)*creg[12], rv*(v3.y+EPS)*creg[13],
                        rv*(v3.z+EPS)*creg[14], rv*(v3.w+EPS)*creg[15]);
        *(float4*)(orow + 12) = o;
    }
}

extern "C" void kernel_launch(void* const* d_in, const int* in_sizes, int n_in,
                              void* d_out, int out_size, void* d_ws, size_t ws_size,
                              hipStream_t stream) {
    const float* x = (const float*)d_in[0];
    float* out  = (float*)d_out;
    float* part = (float*)d_ws;
    float* c    = part + BATCH * NCH * N;
    int*   bar  = (int*)(c + BATCH * N);

    // zero barrier counters every call (graph-capturable stream op)
    hipMemsetAsync(bar, 0, 2 * ITERS * BATCH * sizeof(int), stream);

    sink_persistent<<<dim3(NCH, BATCH), 256, 0, stream>>>(x, part, c, bar, out);
}

// Round 9
// 207.329 us; speedup vs baseline: 14.6851x; 4.7596x over previous
//
#include <hip/hip_runtime.h>

#define BATCH 32
#define N 1024
#define EPS 0.001f
#define TR 64              // rows per block
#define NCH (N / TR)       // 16 chunks per batch; grid = 16 x 32 = 512 blocks
#define HQ 32              // rows per colsum half

typedef float v2f __attribute__((vector_size(8)));

// ws layout (bytes):
//   xq    [BATCH*N*N] fp8 e4m3 = 33,554,432
//   partA [BATCH*NCH*N] f32    =  2,097,152
//   partB [BATCH*NCH*N] f32    =  2,097,152
//   r     [BATCH*N] f32        =    131,072
//
// Sequence (11 dispatches, kernel boundaries are the only global syncs):
//   k_first: read x, write xq=fp8(x+eps), r1=1/(M*1) exact, part1=M^T r1
//   k_iter x9: prologue reduces prev part -> c (redundant per block, L2-hit),
//              rowsum from xq, colsum from xq (own slice, L2-hit), next part
//   k_final: prologue reduces part10 -> c10, out = r10*(x+eps)*c10 (fp32)

__device__ __forceinline__ float dot16_fp8(const int4 raw, const float* creg) {
    float s = 0.0f;
    v2f f;
    f = __builtin_amdgcn_cvt_pk_f32_fp8(raw.x, false); s += creg[0]*f[0]  + creg[1]*f[1];
    f = __builtin_amdgcn_cvt_pk_f32_fp8(raw.x, true);  s += creg[2]*f[0]  + creg[3]*f[1];
    f = __builtin_amdgcn_cvt_pk_f32_fp8(raw.y, false); s += creg[4]*f[0]  + creg[5]*f[1];
    f = __builtin_amdgcn_cvt_pk_f32_fp8(raw.y, true);  s += creg[6]*f[0]  + creg[7]*f[1];
    f = __builtin_amdgcn_cvt_pk_f32_fp8(raw.z, false); s += creg[8]*f[0]  + creg[9]*f[1];
    f = __builtin_amdgcn_cvt_pk_f32_fp8(raw.z, true);  s += creg[10]*f[0] + creg[11]*f[1];
    f = __builtin_amdgcn_cvt_pk_f32_fp8(raw.w, false); s += creg[12]*f[0] + creg[13]*f[1];
    f = __builtin_amdgcn_cvt_pk_f32_fp8(raw.w, true);  s += creg[14]*f[0] + creg[15]*f[1];
    return s;
}

// ---- K1: convert + iteration 1 (c0 = 1) ----
__global__ __launch_bounds__(512, 4)
void k_first(const float* __restrict__ x, unsigned char* __restrict__ xq,
             float* __restrict__ part) {
    __shared__ __align__(16) unsigned char tile[TR * N];   // 64 KB
    __shared__ float r_sh[TR];
    __shared__ float red[N];
    const int chunk = blockIdx.x, b = blockIdx.y;
    const int tid = threadIdx.x, wave = tid >> 6, lane = tid & 63;
    const int j0 = lane * 16;
    const size_t row0 = (size_t)b * N + (size_t)chunk * TR;

    for (int il = 0; il < TR / 8; ++il) {           // 8 rows per wave
        const int rl = wave * (TR / 8) + il;
        const float* xr = x + (row0 + rl) * N + j0;
        float4 v0 = *(const float4*)(xr);
        float4 v1 = *(const float4*)(xr + 4);
        float4 v2 = *(const float4*)(xr + 8);
        float4 v3 = *(const float4*)(xr + 12);
        float a0=v0.x+EPS, a1=v0.y+EPS, a2=v0.z+EPS, a3=v0.w+EPS;
        float a4=v1.x+EPS, a5=v1.y+EPS, a6=v1.z+EPS, a7=v1.w+EPS;
        float a8=v2.x+EPS, a9=v2.y+EPS, a10=v2.z+EPS, a11=v2.w+EPS;
        float a12=v3.x+EPS, a13=v3.y+EPS, a14=v3.z+EPS, a15=v3.w+EPS;
        int4 q;
        q.x = __builtin_amdgcn_cvt_pk_fp8_f32(a0, a1, 0, false);
        q.x = __builtin_amdgcn_cvt_pk_fp8_f32(a2, a3, q.x, true);
        q.y = __builtin_amdgcn_cvt_pk_fp8_f32(a4, a5, 0, false);
        q.y = __builtin_amdgcn_cvt_pk_fp8_f32(a6, a7, q.y, true);
        q.z = __builtin_amdgcn_cvt_pk_fp8_f32(a8, a9, 0, false);
        q.z = __builtin_amdgcn_cvt_pk_fp8_f32(a10, a11, q.z, true);
        q.w = __builtin_amdgcn_cvt_pk_fp8_f32(a12, a13, 0, false);
        q.w = __builtin_amdgcn_cvt_pk_fp8_f32(a14, a15, q.w, true);
        *(int4*)(&tile[rl * N + j0]) = q;
        *(int4*)(xq + (row0 + rl) * N + j0) = q;
        float sum = ((a0+a1)+(a2+a3)) + ((a4+a5)+(a6+a7))
                  + ((a8+a9)+(a10+a11)) + ((a12+a13)+(a14+a15));
#pragma unroll
        for (int off = 32; off; off >>= 1) sum += __shfl_xor(sum, off);
        if (!lane) r_sh[rl] = 1.0f / sum;
    }
    __syncthreads();

    // colsum from LDS tile (halves h=0/1, 32 rows each)
    const int h = tid >> 8, jc = (tid & 255) * 4;
    float s0 = 0, s1 = 0, s2 = 0, s3 = 0;
    for (int i = 0; i < HQ; ++i) {
        const int row = h * HQ + i;
        const float rv = r_sh[row];
        int w = *(const int*)(&tile[row * N + jc]);
        v2f f01 = __builtin_amdgcn_cvt_pk_f32_fp8(w, false);
        v2f f23 = __builtin_amdgcn_cvt_pk_f32_fp8(w, true);
        s0 += rv * f01[0];  s1 += rv * f01[1];
        s2 += rv * f23[0];  s3 += rv * f23[1];
    }
    if (h == 1) *(float4*)(&red[jc]) = make_float4(s0, s1, s2, s3);
    __syncthreads();
    if (h == 0) {
        float4 rr = *(const float4*)(&red[jc]);
        *(float4*)(part + ((size_t)(b * NCH + chunk)) * N + jc) =
            make_float4(s0 + rr.x, s1 + rr.y, s2 + rr.z, s3 + rr.w);
    }
}

// ---- K2..K10: prologue c-reduce, rowsum, colsum (tile-less) ----
template<bool WRITE_R>
__global__ __launch_bounds__(512, 4)
void k_iter(const unsigned char* __restrict__ xq,
            const float* __restrict__ part_in,
            float* __restrict__ part_out,
            float* __restrict__ r_out) {
    __shared__ float c_sh[N];
    __shared__ float r_sh[TR];
    __shared__ float red[N];
    const int chunk = blockIdx.x, b = blockIdx.y;
    const int tid = threadIdx.x, wave = tid >> 6, lane = tid & 63;
    const int j0 = lane * 16;
    const size_t row0 = (size_t)b * N + (size_t)chunk * TR;

    // prologue: c[b,:] = 1/colsum(part_in) — redundant per block, cached reads
    {
        const int j = tid * 2;
        const float* pp = part_in + (size_t)b * NCH * N + j;
        float sA = 0.0f, sB = 0.0f;
#pragma unroll
        for (int ch = 0; ch < NCH; ++ch) {
            float2 v = *(const float2*)(pp + (size_t)ch * N);
            sA += v.x;  sB += v.y;
        }
        c_sh[j]     = 1.0f / sA;
        c_sh[j + 1] = 1.0f / sB;
    }
    __syncthreads();

    // rowsum: r = 1/(M c)
    float creg[16];
#pragma unroll
    for (int k = 0; k < 16; ++k) creg[k] = c_sh[j0 + k];
    for (int il = 0; il < TR / 8; ++il) {
        const int rl = wave * (TR / 8) + il;
        int4 raw = *(const int4*)(xq + (row0 + rl) * N + j0);
        float sum = dot16_fp8(raw, creg);
#pragma unroll
        for (int off = 32; off; off >>= 1) sum += __shfl_xor(sum, off);
        if (!lane) r_sh[rl] = 1.0f / sum;
    }
    __syncthreads();
    if (WRITE_R && tid < TR) r_out[row0 + tid] = r_sh[tid];

    // colsum from global xq (block's own slice — L2-resident)
    const int h = tid >> 8, jc = (tid & 255) * 4;
    float s0 = 0, s1 = 0, s2 = 0, s3 = 0;
    for (int i = 0; i < HQ; ++i) {
        const int row = h * HQ + i;
        const float rv = r_sh[row];
        int w = *(const int*)(xq + (row0 + row) * N + jc);
        v2f f01 = __builtin_amdgcn_cvt_pk_f32_fp8(w, false);
        v2f f23 = __builtin_amdgcn_cvt_pk_f32_fp8(w, true);
        s0 += rv * f01[0];  s1 += rv * f01[1];
        s2 += rv * f23[0];  s3 += rv * f23[1];
    }
    if (h == 1) *(float4*)(&red[jc]) = make_float4(s0, s1, s2, s3);
    __syncthreads();
    if (h == 0) {
        float4 rr = *(const float4*)(&red[jc]);
        *(float4*)(part_out + ((size_t)(b * NCH + chunk)) * N + jc) =
            make_float4(s0 + rr.x, s1 + rr.y, s2 + rr.z, s3 + rr.w);
    }
}

// ---- K11: prologue c-reduce, then out = r*(x+eps)*c in full fp32 ----
__global__ __launch_bounds__(512, 4)
void k_final(const float* __restrict__ x,
             const float* __restrict__ part_in,
             const float* __restrict__ r,
             float* __restrict__ out) {
    __shared__ float c_sh[N];
    const int chunk = blockIdx.x, b = blockIdx.y;
    const int tid = threadIdx.x, wave = tid >> 6, lane = tid & 63;
    const int j0 = lane * 16;
    const size_t row0 = (size_t)b * N + (size_t)chunk * TR;

    {
        const int j = tid * 2;
        const float* pp = part_in + (size_t)b * NCH * N + j;
        float sA = 0.0f, sB = 0.0f;
#pragma unroll
        for (int ch = 0; ch < NCH; ++ch) {
            float2 v = *(const float2*)(pp + (size_t)ch * N);
            sA += v.x;  sB += v.y;
        }
        c_sh[j]     = 1.0f / sA;
        c_sh[j + 1] = 1.0f / sB;
    }
    __syncthreads();

    float creg[16];
#pragma unroll
    for (int k = 0; k < 16; ++k) creg[k] = c_sh[j0 + k];
    for (int il = 0; il < TR / 8; ++il) {
        const int rl = wave * (TR / 8) + il;
        const float rv = r[row0 + rl];
        const float* xr = x + (row0 + rl) * N + j0;
        float* orow = out + (row0 + rl) * N + j0;
        float4 v0 = *(const float4*)(xr);
        float4 v1 = *(const float4*)(xr + 4);
        float4 v2 = *(const float4*)(xr + 8);
        float4 v3 = *(const float4*)(xr + 12);
        *(float4*)(orow) = make_float4(
            rv*(v0.x+EPS)*creg[0],  rv*(v0.y+EPS)*creg[1],
            rv*(v0.z+EPS)*creg[2],  rv*(v0.w+EPS)*creg[3]);
        *(float4*)(orow + 4) = make_float4(
            rv*(v1.x+EPS)*creg[4],  rv*(v1.y+EPS)*creg[5],
            rv*(v1.z+EPS)*creg[6],  rv*(v1.w+EPS)*creg[7]);
        *(float4*)(orow + 8) = make_float4(
            rv*(v2.x+EPS)*creg[8],  rv*(v2.y+EPS)*creg[9],
            rv*(v2.z+EPS)*creg[10], rv*(v2.w+EPS)*creg[11]);
        *(float4*)(orow + 12) = make_float4(
            rv*(v3.x+EPS)*creg[12], rv*(v3.y+EPS)*creg[13],
            rv*(v3.z+EPS)*creg[14], rv*(v3.w+EPS)*creg[15]);
    }
}

extern "C" void kernel_launch(void* const* d_in, const int* in_sizes, int n_in,
                              void* d_out, int out_size, void* d_ws, size_t ws_size,
                              hipStream_t stream) {
    const float* x = (const float*)d_in[0];
    float* out = (float*)d_out;

    unsigned char* xq = (unsigned char*)d_ws;
    float* partA = (float*)((char*)d_ws + (size_t)BATCH * N * N);
    float* partB = partA + BATCH * NCH * N;
    float* r     = partB + BATCH * NCH * N;

    dim3 grid(NCH, BATCH);   // 16 x 32 = 512 blocks

    k_first<<<grid, 512, 0, stream>>>(x, xq, partA);
    float* pin = partA;
    float* pout = partB;
    for (int t = 2; t <= 10; ++t) {
        if (t < 10)
            k_iter<false><<<grid, 512, 0, stream>>>(xq, pin, pout, nullptr);
        else
            k_iter<true><<<grid, 512, 0, stream>>>(xq, pin, pout, r);
        float* tmp = pin; pin = pout; pout = tmp;
    }
    k_final<<<grid, 512, 0, stream>>>(x, pin, r, out);
}

// Round 10
// 201.912 us; speedup vs baseline: 15.0791x; 1.0268x over previous
//
#include <hip/hip_runtime.h>

#define BATCH 32
#define N 1024
#define EPS 0.001f
#define TR 64              // rows per block
#define NCH (N / TR)       // 16 chunks per batch; grid = 16 x 32 = 512 blocks
#define NW 8               // waves per block (512 threads)

typedef float v2f __attribute__((vector_size(8)));

// ws layout (bytes):
//   xq    [BATCH*N*N] fp8 e4m3 = 33,554,432
//   partA [BATCH*NCH*N] f32    =  2,097,152
//   partB [BATCH*NCH*N] f32    =  2,097,152
//   r     [BATCH*N] f32        =    131,072
//
// 11 dispatches; kernel boundaries are the only global syncs. Each iteration
// kernel reads xq exactly ONCE: per row, rowsum wave-reduce completes, all
// lanes hold the total -> immediately accumulate rv*f[k] into 16 per-lane
// column accumulators from the same decoded registers. Per-wave column
// partials combine via a 32 KB LDS buffer (lane-contiguous float4 stores).
//
// red layout: red[w][kk*256 + l*4 + e] holds wave w's partial for column
// l*16 + kk*4 + e  (l = lane, kk = 0..3, e = 0..3).
// Inverse for column c: idx = ((c&15)>>2)*256 + (c>>4)*4 + (c&3).

// ---- K1: convert + iteration 1 (c0 = 1, exact fp32 values) ----
__global__ __launch_bounds__(512, 4)
void k_first(const float* __restrict__ x, unsigned char* __restrict__ xq,
             float* __restrict__ part) {
    __shared__ float red[NW * N];          // 32 KB
    const int chunk = blockIdx.x, b = blockIdx.y;
    const int tid = threadIdx.x, wave = tid >> 6, lane = tid & 63;
    const int j0 = lane * 16;
    const size_t row0 = (size_t)b * N + (size_t)chunk * TR;

    float acc[16];
#pragma unroll
    for (int k = 0; k < 16; ++k) acc[k] = 0.0f;

    for (int il = 0; il < TR / NW; ++il) {
        const int row = wave * (TR / NW) + il;
        const float* xr = x + (row0 + row) * N + j0;
        float4 v0 = *(const float4*)(xr);
        float4 v1 = *(const float4*)(xr + 4);
        float4 v2 = *(const float4*)(xr + 8);
        float4 v3 = *(const float4*)(xr + 12);
        float a[16];
        a[0]=v0.x+EPS;  a[1]=v0.y+EPS;  a[2]=v0.z+EPS;  a[3]=v0.w+EPS;
        a[4]=v1.x+EPS;  a[5]=v1.y+EPS;  a[6]=v1.z+EPS;  a[7]=v1.w+EPS;
        a[8]=v2.x+EPS;  a[9]=v2.y+EPS;  a[10]=v2.z+EPS; a[11]=v2.w+EPS;
        a[12]=v3.x+EPS; a[13]=v3.y+EPS; a[14]=v3.z+EPS; a[15]=v3.w+EPS;
        int4 q;
        q.x = __builtin_amdgcn_cvt_pk_fp8_f32(a[0],  a[1],  0,   false);
        q.x = __builtin_amdgcn_cvt_pk_fp8_f32(a[2],  a[3],  q.x, true);
        q.y = __builtin_amdgcn_cvt_pk_fp8_f32(a[4],  a[5],  0,   false);
        q.y = __builtin_amdgcn_cvt_pk_fp8_f32(a[6],  a[7],  q.y, true);
        q.z = __builtin_amdgcn_cvt_pk_fp8_f32(a[8],  a[9],  0,   false);
        q.z = __builtin_amdgcn_cvt_pk_fp8_f32(a[10], a[11], q.z, true);
        q.w = __builtin_amdgcn_cvt_pk_fp8_f32(a[12], a[13], 0,   false);
        q.w = __builtin_amdgcn_cvt_pk_fp8_f32(a[14], a[15], q.w, true);
        *(int4*)(xq + (row0 + row) * N + j0) = q;
        float sum = ((a[0]+a[1])+(a[2]+a[3])) + ((a[4]+a[5])+(a[6]+a[7]))
                  + ((a[8]+a[9])+(a[10]+a[11])) + ((a[12]+a[13])+(a[14]+a[15]));
#pragma unroll
        for (int off = 32; off; off >>= 1) sum += __shfl_xor(sum, off);
        const float rv = 1.0f / sum;
#pragma unroll
        for (int k = 0; k < 16; ++k) acc[k] += rv * a[k];
    }

    // wave-combine
    {
        float* rw = red + wave * N;
#pragma unroll
        for (int kk = 0; kk < 4; ++kk)
            *(float4*)(rw + kk * 256 + lane * 4) =
                make_float4(acc[kk*4+0], acc[kk*4+1], acc[kk*4+2], acc[kk*4+3]);
    }
    __syncthreads();
    {
        const int j = tid * 2;
        const int i0 = ((j & 15) >> 2) * 256 + (j >> 4) * 4 + (j & 3);
        const int j1 = j + 1;
        const int i1 = ((j1 & 15) >> 2) * 256 + (j1 >> 4) * 4 + (j1 & 3);
        float s0 = 0.0f, s1 = 0.0f;
#pragma unroll
        for (int w = 0; w < NW; ++w) {
            s0 += red[w * N + i0];
            s1 += red[w * N + i1];
        }
        *(float2*)(part + ((size_t)(b * NCH + chunk)) * N + j) =
            make_float2(s0, s1);
    }
}

// ---- K2..K10: prologue c-reduce, then single-read fused row+col pass ----
template<bool WRITE_R>
__global__ __launch_bounds__(512, 4)
void k_iter(const unsigned char* __restrict__ xq,
            const float* __restrict__ part_in,
            float* __restrict__ part_out,
            float* __restrict__ r_out) {
    __shared__ float c_sh[N];
    __shared__ float red[NW * N];          // 32 KB
    const int chunk = blockIdx.x, b = blockIdx.y;
    const int tid = threadIdx.x, wave = tid >> 6, lane = tid & 63;
    const int j0 = lane * 16;
    const size_t row0 = (size_t)b * N + (size_t)chunk * TR;

    // prologue: c[b,:] = 1/colsum(part_in) — redundant per block, cached
    {
        const int j = tid * 2;
        const float* pp = part_in + (size_t)b * NCH * N + j;
        float sA = 0.0f, sB = 0.0f;
#pragma unroll
        for (int ch = 0; ch < NCH; ++ch) {
            float2 v = *(const float2*)(pp + (size_t)ch * N);
            sA += v.x;  sB += v.y;
        }
        c_sh[j]     = 1.0f / sA;
        c_sh[j + 1] = 1.0f / sB;
    }
    __syncthreads();

    float creg[16];
#pragma unroll
    for (int k = 0; k < 16; ++k) creg[k] = c_sh[j0 + k];

    float acc[16];
#pragma unroll
    for (int k = 0; k < 16; ++k) acc[k] = 0.0f;

    for (int il = 0; il < TR / NW; ++il) {
        const int row = wave * (TR / NW) + il;
        int4 raw = *(const int4*)(xq + (row0 + row) * N + j0);
        float f[16];
        v2f d;
        d = __builtin_amdgcn_cvt_pk_f32_fp8(raw.x, false); f[0]=d[0];  f[1]=d[1];
        d = __builtin_amdgcn_cvt_pk_f32_fp8(raw.x, true);  f[2]=d[0];  f[3]=d[1];
        d = __builtin_amdgcn_cvt_pk_f32_fp8(raw.y, false); f[4]=d[0];  f[5]=d[1];
        d = __builtin_amdgcn_cvt_pk_f32_fp8(raw.y, true);  f[6]=d[0];  f[7]=d[1];
        d = __builtin_amdgcn_cvt_pk_f32_fp8(raw.z, false); f[8]=d[0];  f[9]=d[1];
        d = __builtin_amdgcn_cvt_pk_f32_fp8(raw.z, true);  f[10]=d[0]; f[11]=d[1];
        d = __builtin_amdgcn_cvt_pk_f32_fp8(raw.w, false); f[12]=d[0]; f[13]=d[1];
        d = __builtin_amdgcn_cvt_pk_f32_fp8(raw.w, true);  f[14]=d[0]; f[15]=d[1];
        float sum = 0.0f;
#pragma unroll
        for (int k = 0; k < 16; ++k) sum += f[k] * creg[k];
#pragma unroll
        for (int off = 32; off; off >>= 1) sum += __shfl_xor(sum, off);
        const float rv = 1.0f / sum;
        if (WRITE_R && !lane) r_out[row0 + row] = rv;
#pragma unroll
        for (int k = 0; k < 16; ++k) acc[k] += rv * f[k];
    }

    // wave-combine
    {
        float* rw = red + wave * N;
#pragma unroll
        for (int kk = 0; kk < 4; ++kk)
            *(float4*)(rw + kk * 256 + lane * 4) =
                make_float4(acc[kk*4+0], acc[kk*4+1], acc[kk*4+2], acc[kk*4+3]);
    }
    __syncthreads();
    {
        const int j = tid * 2;
        const int i0 = ((j & 15) >> 2) * 256 + (j >> 4) * 4 + (j & 3);
        const int j1 = j + 1;
        const int i1 = ((j1 & 15) >> 2) * 256 + (j1 >> 4) * 4 + (j1 & 3);
        float s0 = 0.0f, s1 = 0.0f;
#pragma unroll
        for (int w = 0; w < NW; ++w) {
            s0 += red[w * N + i0];
            s1 += red[w * N + i1];
        }
        *(float2*)(part_out + ((size_t)(b * NCH + chunk)) * N + j) =
            make_float2(s0, s1);
    }
}

// ---- K11: prologue c-reduce, then out = r*(x+eps)*c in full fp32 ----
__global__ __launch_bounds__(512, 4)
void k_final(const float* __restrict__ x,
             const float* __restrict__ part_in,
             const float* __restrict__ r,
             float* __restrict__ out) {
    __shared__ float c_sh[N];
    const int chunk = blockIdx.x, b = blockIdx.y;
    const int tid = threadIdx.x, wave = tid >> 6, lane = tid & 63;
    const int j0 = lane * 16;
    const size_t row0 = (size_t)b * N + (size_t)chunk * TR;

    {
        const int j = tid * 2;
        const float* pp = part_in + (size_t)b * NCH * N + j;
        float sA = 0.0f, sB = 0.0f;
#pragma unroll
        for (int ch = 0; ch < NCH; ++ch) {
            float2 v = *(const float2*)(pp + (size_t)ch * N);
            sA += v.x;  sB += v.y;
        }
        c_sh[j]     = 1.0f / sA;
        c_sh[j + 1] = 1.0f / sB;
    }
    __syncthreads();

    float creg[16];
#pragma unroll
    for (int k = 0; k < 16; ++k) creg[k] = c_sh[j0 + k];
    for (int il = 0; il < TR / NW; ++il) {
        const int rl = wave * (TR / NW) + il;
        const float rv = r[row0 + rl];
        const float* xr = x + (row0 + rl) * N + j0;
        float* orow = out + (row0 + rl) * N + j0;
        float4 v0 = *(const float4*)(xr);
        float4 v1 = *(const float4*)(xr + 4);
        float4 v2 = *(const float4*)(xr + 8);
        float4 v3 = *(const float4*)(xr + 12);
        *(float4*)(orow) = make_float4(
            rv*(v0.x+EPS)*creg[0],  rv*(v0.y+EPS)*creg[1],
            rv*(v0.z+EPS)*creg[2],  rv*(v0.w+EPS)*creg[3]);
        *(float4*)(orow + 4) = make_float4(
            rv*(v1.x+EPS)*creg[4],  rv*(v1.y+EPS)*creg[5],
            rv*(v1.z+EPS)*creg[6],  rv*(v1.w+EPS)*creg[7]);
        *(float4*)(orow + 8) = make_float4(
            rv*(v2.x+EPS)*creg[8],  rv*(v2.y+EPS)*creg[9],
            rv*(v2.z+EPS)*creg[10], rv*(v2.w+EPS)*creg[11]);
        *(float4*)(orow + 12) = make_float4(
            rv*(v3.x+EPS)*creg[12], rv*(v3.y+EPS)*creg[13],
            rv*(v3.z+EPS)*creg[14], rv*(v3.w+EPS)*creg[15]);
    }
}

extern "C" void kernel_launch(void* const* d_in, const int* in_sizes, int n_in,
                              void* d_out, int out_size, void* d_ws, size_t ws_size,
                              hipStream_t stream) {
    const float* x = (const float*)d_in[0];
    float* out = (float*)d_out;

    unsigned char* xq = (unsigned char*)d_ws;
    float* partA = (float*)((char*)d_ws + (size_t)BATCH * N * N);
    float* partB = partA + BATCH * NCH * N;
    float* r     = partB + BATCH * NCH * N;

    dim3 grid(NCH, BATCH);   // 16 x 32 = 512 blocks

    k_first<<<grid, 512, 0, stream>>>(x, xq, partA);
    float* pin = partA;
    float* pout = partB;
    for (int t = 2; t <= 10; ++t) {
        if (t < 10)
            k_iter<false><<<grid, 512, 0, stream>>>(xq, pin, pout, nullptr);
        else
            k_iter<true><<<grid, 512, 0, stream>>>(xq, pin, pout, r);
        float* tmp = pin; pin = pout; pout = tmp;
    }
    k_final<<<grid, 512, 0, stream>>>(x, pin, r, out);
}